// Round 1
// baseline (1414.402 us; speedup 1.0000x reference)
//
#include <hip/hip_runtime.h>
#include <hip/hip_bf16.h>

typedef __attribute__((ext_vector_type(8))) short short8;
typedef __attribute__((ext_vector_type(4))) float f32x4;

__device__ __forceinline__ unsigned short f2bf(float v) {
    __hip_bfloat16 h = __float2bfloat16(v);   // RNE
    return *reinterpret_cast<unsigned short*>(&h);
}
__device__ __forceinline__ float bf2f(unsigned short u) {
    union { unsigned int i; float f; } x;
    x.i = (unsigned int)u << 16;
    return x.f;
}

constexpr int MAXB = 2048;   // max fine buckets (N/64 = 1563 here)
constexpr int SP   = 66;     // LDS accumulator row stride (floats); 66%32=2 -> spread banks

// ---------------------------------------------------------------------------
// Weight pre-transpose: Wt[(r*H + h)*64 + d] = bf16( r<R ? W[r][d][h]
//                                                        : Wself[d][h] ).
// ---------------------------------------------------------------------------
template<int H>
__global__ __launch_bounds__(256) void transpose_w(
    const float* __restrict__ W, const float* __restrict__ Wself,
    unsigned short* __restrict__ Wt, int R)
{
    int i = blockIdx.x * 256 + threadIdx.x;
    int total = (R + 1) * H * 64;
    if (i >= total) return;
    int d = i & 63;
    int hh = i >> 6;               // r*H + h
    int r = hh / H, h = hh % H;    // H compile-time -> shifts
    float v = (r < R) ? W[((size_t)r * 64 + d) * H + h]
                      : Wself[(size_t)d * H + h];
    Wt[i] = f2bf(v);
}

// ---------------------------------------------------------------------------
// Cast feat fp32 -> bf16 rows (gather source for layer 1). 8 elems/thread.
// ---------------------------------------------------------------------------
__global__ __launch_bounds__(256) void cast_bf16x8(
    const float* __restrict__ in, unsigned short* __restrict__ outp, int n8)
{
    int i = blockIdx.x * 256 + threadIdx.x;
    if (i >= n8) return;
    const float4 a = ((const float4*)in)[(size_t)i * 2];
    const float4 b = ((const float4*)in)[(size_t)i * 2 + 1];
    short8 u;
    u[0] = (short)f2bf(a.x); u[1] = (short)f2bf(a.y);
    u[2] = (short)f2bf(a.z); u[3] = (short)f2bf(a.w);
    u[4] = (short)f2bf(b.x); u[5] = (short)f2bf(b.y);
    u[6] = (short)f2bf(b.z); u[7] = (short)f2bf(b.w);
    *(short8*)&outp[(size_t)i * 8] = u;
}

// ---------------------------------------------------------------------------
// Bucket partition. Bucket = 64 consecutive dst nodes.
// Record: (et << 23) | (src << 6) | (dst & 63).   (et<8, src<2^17)
// ---------------------------------------------------------------------------
__global__ __launch_bounds__(256) void zero_int(int* __restrict__ p, int n) {
    int i = blockIdx.x * 256 + threadIdx.x;
    if (i < n) p[i] = 0;
}

__global__ __launch_bounds__(256) void fine_hist(
    const int* __restrict__ dst, int* __restrict__ ghist, int E, int B, int CH)
{
    __shared__ int hist[MAXB];
    const int t = threadIdx.x;
    const int e0 = blockIdx.x * CH, e1 = min(E, e0 + CH);
    for (int i = t; i < B; i += 256) hist[i] = 0;
    __syncthreads();
    for (int e = e0 + t; e < e1; e += 256) atomicAdd(&hist[dst[e] >> 6], 1);
    __syncthreads();
    for (int i = t; i < B; i += 256) {
        int h = hist[i];
        if (h) atomicAdd(&ghist[i], h);
    }
}

__global__ __launch_bounds__(256) void fine_scan(
    const int* __restrict__ ghist, int* __restrict__ bstart,
    int* __restrict__ cursor, int B, int E)
{
    __shared__ int ts[256];
    const int t = threadIdx.x;
    const int PER = (B + 255) / 256;   // <= 8
    int loc[8];
    int s = 0;
    for (int j = 0; j < PER; ++j) {
        int i = t * PER + j;
        loc[j] = (i < B) ? ghist[i] : 0;
        s += loc[j];
    }
    ts[t] = s;
    __syncthreads();
    for (int off = 1; off < 256; off <<= 1) {
        int x = (t >= off) ? ts[t - off] : 0;
        __syncthreads();
        ts[t] += x;
        __syncthreads();
    }
    int run = ts[t] - s;
    for (int j = 0; j < PER; ++j) {
        int i = t * PER + j;
        if (i < B) { bstart[i] = run; cursor[i] = run; }
        run += loc[j];
    }
    if (t == 255) bstart[B] = E;
}

__global__ __launch_bounds__(256) void partition_fine(
    const int* __restrict__ src, const int* __restrict__ dst,
    const int* __restrict__ et, int* __restrict__ cursor,
    int* __restrict__ rec, int E, int N, int B, int CH)
{
    __shared__ int hist[MAXB];
    __shared__ int base[MAXB];
    __shared__ int cnt[MAXB];
    const int t = threadIdx.x;
    const int e0 = blockIdx.x * CH, e1 = min(E, e0 + CH);

    for (int i = t; i < B; i += 256) hist[i] = 0;
    __syncthreads();
    for (int e = e0 + t; e < e1; e += 256) atomicAdd(&hist[dst[e] >> 6], 1);
    __syncthreads();
    for (int i = t; i < B; i += 256) {
        int h = hist[i];
        base[i] = h ? atomicAdd(&cursor[i], h) : 0;
        cnt[i] = 0;
    }
    __syncthreads();
    for (int e = e0 + t; e < e1; e += 256) {
        int d = dst[e];
        int b = d >> 6;
        int pos = base[b] + atomicAdd(&cnt[b], 1);
        rec[pos] = (et[e] << 23) | (src[e] << 6) | (d & 63);
    }
}

// ---------------------------------------------------------------------------
// Per-bucket 8-bin counting sort by relation.
// eidx[pos] = (src << 6) | dstlocal, grouped by (bucket, relation);
// brp[b*(R+1) + r] = start offset of relation r within bucket b.
// ---------------------------------------------------------------------------
__global__ __launch_bounds__(256) void bucket_sort_rel(
    const int* __restrict__ bstart, const int* __restrict__ rec,
    int* __restrict__ eidx, int* __restrict__ brp, int R)
{
    __shared__ int hist[16];
    __shared__ int excl[17];
    __shared__ int cur[16];
    const int b = blockIdx.x;
    const int tid = threadIdx.x;
    const int p0 = bstart[b], p1 = bstart[b + 1];

    if (tid < 16) hist[tid] = 0;
    __syncthreads();
    for (int p = p0 + tid; p < p1; p += 256)
        atomicAdd(&hist[rec[p] >> 23], 1);
    __syncthreads();
    if (tid == 0) {
        int run = 0;
        for (int i = 0; i < R; ++i) { excl[i] = run; run += hist[i]; }
        excl[R] = run;
    }
    __syncthreads();
    if (tid <= R) {
        brp[b * (R + 1) + tid] = p0 + excl[tid];
        if (tid < R) cur[tid] = excl[tid];
    }
    __syncthreads();
    for (int p = p0 + tid; p < p1; p += 256) {
        int rv = rec[p];
        int pos = p0 + atomicAdd(&cur[rv >> 23], 1);
        eidx[pos] = rv & 0x7FFFFF;   // (src<<6) | dstlocal
    }
}

// ---------------------------------------------------------------------------
// Edge aggregation into LDS: half-wave (32 lanes) per edge, lane holds a
// packed uint (2 bf16 cols); ds_add_f32 into S[dl][2c],S[dl][2c+1].
// 4-deep unroll for MLP; edges of one (bucket, relation) range.
// ---------------------------------------------------------------------------
__device__ __forceinline__ void agg_range(
    const unsigned int* __restrict__ in32, const int* __restrict__ eidx,
    float* __restrict__ S, int q0, int q1, int hwv, int c)
{
    int p = q0 + hwv;
    for (; p + 24 < q1; p += 32) {
        int r0 = eidx[p], r1 = eidx[p + 8], r2 = eidx[p + 16], r3 = eidx[p + 24];
        unsigned int v0 = in32[(size_t)(r0 >> 6) * 32 + c];
        unsigned int v1 = in32[(size_t)(r1 >> 6) * 32 + c];
        unsigned int v2 = in32[(size_t)(r2 >> 6) * 32 + c];
        unsigned int v3 = in32[(size_t)(r3 >> 6) * 32 + c];
        int b0 = (r0 & 63) * SP + 2 * c;
        int b1 = (r1 & 63) * SP + 2 * c;
        int b2 = (r2 & 63) * SP + 2 * c;
        int b3 = (r3 & 63) * SP + 2 * c;
        atomicAdd(&S[b0],     bf2f((unsigned short)(v0 & 0xffff)));
        atomicAdd(&S[b0 + 1], bf2f((unsigned short)(v0 >> 16)));
        atomicAdd(&S[b1],     bf2f((unsigned short)(v1 & 0xffff)));
        atomicAdd(&S[b1 + 1], bf2f((unsigned short)(v1 >> 16)));
        atomicAdd(&S[b2],     bf2f((unsigned short)(v2 & 0xffff)));
        atomicAdd(&S[b2 + 1], bf2f((unsigned short)(v2 >> 16)));
        atomicAdd(&S[b3],     bf2f((unsigned short)(v3 & 0xffff)));
        atomicAdd(&S[b3 + 1], bf2f((unsigned short)(v3 >> 16)));
    }
    for (; p < q1; p += 8) {
        int r0 = eidx[p];
        unsigned int v0 = in32[(size_t)(r0 >> 6) * 32 + c];
        int b0 = (r0 & 63) * SP + 2 * c;
        atomicAdd(&S[b0],     bf2f((unsigned short)(v0 & 0xffff)));
        atomicAdd(&S[b0 + 1], bf2f((unsigned short)(v0 >> 16)));
    }
}

// ---------------------------------------------------------------------------
// Fused aggregate-then-transform layer. One block = one bucket (64 dst).
// Per relation r: S[64][64] = sum of bf16 input rows of sources (ds_add_f32),
// then acc += bf16(S) @ W_r via MFMA (operand-swapped, same fragment formulas
// as the verified gemm_rel_mfma). Self term reads input rows directly from
// global. Output staged in LDS for coalesced 16B stores.
// BF16OUT: layer1 (relu + bf16 h1). !BF16OUT: layer2 (fp32 out).
// ---------------------------------------------------------------------------
template<int HOUT, bool BF16OUT>
__global__ __launch_bounds__(256) void fused_layer(
    const unsigned short* __restrict__ inb,   // bf16 input rows [N][64]
    const unsigned short* __restrict__ Wt,    // [(R+1)*HOUT][64] bf16
    const float* __restrict__ bias,           // [HOUT]
    const int* __restrict__ brp,              // [B][R+1]
    const int* __restrict__ eidx,             // (src<<6)|dl, (bucket,rel)-grouped
    void* __restrict__ outp,
    int N, int R)
{
    alignas(16) __shared__ float S[64 * SP];
    __shared__ int qs[17];

    const unsigned int* in32 = (const unsigned int*)inb;
    const int b = blockIdx.x;
    const int tid = threadIdx.x;
    const int n0 = b * 64;
    const int w = tid >> 6, lane = tid & 63;
    const int m = lane & 15, quad = lane >> 4;
    const int hwv = tid >> 5, c = tid & 31;

    if (tid <= R) qs[tid] = brp[b * (R + 1) + tid];
    {
        f32x4 z = {0.f, 0.f, 0.f, 0.f};
        for (int i = tid; i < 64 * SP / 4; i += 256) ((f32x4*)S)[i] = z;
    }
    __syncthreads();

    // aggregate relation 0
    agg_range(in32, eidx, S, qs[0], qs[1], hwv, c);
    __syncthreads();

    constexpr int NT = HOUT / 16;
    f32x4 acc[NT];
    #pragma unroll
    for (int nt = 0; nt < NT; ++nt) acc[nt] = (f32x4){0.f, 0.f, 0.f, 0.f};

    auto wptr = [&](int r, int nt, int kc) {
        return (const short8*)&Wt[((size_t)(r * HOUT + nt * 16 + m)) * 64 + kc * 32 + quad * 8];
    };

    for (int r = 0; r < R; ++r) {
        // B-operand fragment from S: col = lane&15 -> node, k = kc*32+quad*8+j
        short8 sf0, sf1;
        const float* Srow = &S[(w * 16 + m) * SP + quad * 8];
        #pragma unroll
        for (int j = 0; j < 8; ++j) sf0[j] = (short)f2bf(Srow[j]);
        #pragma unroll
        for (int j = 0; j < 8; ++j) sf1[j] = (short)f2bf(Srow[32 + j]);

        #pragma unroll
        for (int nt = 0; nt < NT; ++nt) {
            short8 wa = *wptr(r, nt, 0);
            short8 wb = *wptr(r, nt, 1);
            acc[nt] = __builtin_amdgcn_mfma_f32_16x16x32_bf16(wa, sf0, acc[nt], 0, 0, 0);
            acc[nt] = __builtin_amdgcn_mfma_f32_16x16x32_bf16(wb, sf1, acc[nt], 0, 0, 0);
        }

        __syncthreads();   // all waves done reading S for relation r
        if (r + 1 < R) {
            f32x4 z = {0.f, 0.f, 0.f, 0.f};
            for (int i = tid; i < 64 * SP / 4; i += 256) ((f32x4*)S)[i] = z;
            __syncthreads();
            agg_range(in32, eidx, S, qs[r + 1], qs[r + 2], hwv, c);
            __syncthreads();
        }
    }

    // self term: node's own input row, directly from global (bf16)
    const int node = n0 + w * 16 + m;
    short8 se0 = {}, se1 = {};
    if (node < N) {
        se0 = *(const short8*)&inb[(size_t)node * 64 + quad * 8];
        se1 = *(const short8*)&inb[(size_t)node * 64 + 32 + quad * 8];
    }
    #pragma unroll
    for (int nt = 0; nt < NT; ++nt) {
        short8 wa = *wptr(R, nt, 0);
        short8 wb = *wptr(R, nt, 1);
        acc[nt] = __builtin_amdgcn_mfma_f32_16x16x32_bf16(wa, se0, acc[nt], 0, 0, 0);
        acc[nt] = __builtin_amdgcn_mfma_f32_16x16x32_bf16(wb, se1, acc[nt], 0, 0, 0);
    }

    // epilogue: bias (+relu), stage in LDS (stride 36), coalesced 16B stores.
    // D layout (swapped): reg i -> h-col = nt*16 + quad*4 + i, col = lane&15 -> node.
    if constexpr (BF16OUT) {
        unsigned int* Su = (unsigned int*)S;
        const int row = w * 16 + m;
        #pragma unroll
        for (int nt = 0; nt < NT; ++nt) {
            const float4 bv = *(const float4*)&bias[nt * 16 + quad * 4];
            float o0 = fmaxf(acc[nt][0] + bv.x, 0.f);
            float o1 = fmaxf(acc[nt][1] + bv.y, 0.f);
            float o2 = fmaxf(acc[nt][2] + bv.z, 0.f);
            float o3 = fmaxf(acc[nt][3] + bv.w, 0.f);
            int colu = (nt * 16 + quad * 4) >> 1;
            Su[row * 36 + colu]     = (unsigned int)f2bf(o0) | ((unsigned int)f2bf(o1) << 16);
            Su[row * 36 + colu + 1] = (unsigned int)f2bf(o2) | ((unsigned int)f2bf(o3) << 16);
        }
        __syncthreads();
        unsigned int* outu = (unsigned int*)outp;
        #pragma unroll
        for (int it = 0; it < 2; ++it) {
            int i = tid + it * 256;          // 512 x uint4 = 64 rows x 32 uints
            int rw = i >> 3, ch = i & 7;
            int gn = n0 + rw;
            if (gn < N) {
                uint4 v = *(const uint4*)&Su[rw * 36 + ch * 4];
                *(uint4*)&outu[(size_t)gn * 32 + ch * 4] = v;
            }
        }
    } else {
        float* Sf = S;
        const int row = w * 16 + m;
        #pragma unroll
        for (int nt = 0; nt < NT; ++nt) {
            const float4 bv = *(const float4*)&bias[nt * 16 + quad * 4];
            float4 o = make_float4(acc[nt][0] + bv.x, acc[nt][1] + bv.y,
                                   acc[nt][2] + bv.z, acc[nt][3] + bv.w);
            *(float4*)&Sf[row * 36 + nt * 16 + quad * 4] = o;
        }
        __syncthreads();
        float* outf = (float*)outp;
        #pragma unroll
        for (int it = 0; it < 2; ++it) {
            int i = tid + it * 256;          // 512 x float4 = 64 rows x 32 floats
            int rw = i >> 3, ch = i & 7;
            int gn = n0 + rw;
            if (gn < N) {
                float4 v = *(const float4*)&Sf[rw * 36 + ch * 4];
                *(float4*)&outf[(size_t)gn * 32 + ch * 4] = v;
            }
        }
    }
}

extern "C" void kernel_launch(void* const* d_in, const int* in_sizes, int n_in,
                              void* d_out, int out_size, void* d_ws, size_t ws_size,
                              hipStream_t stream)
{
    const float* feat = (const float*)d_in[0];
    const int*   src  = (const int*)d_in[1];
    const int*   dst  = (const int*)d_in[2];
    const int*   et   = (const int*)d_in[3];
    const float* W1   = (const float*)d_in[4];
    const float* Ws1  = (const float*)d_in[5];
    const float* b1   = (const float*)d_in[6];
    const float* W2   = (const float*)d_in[7];
    const float* Ws2  = (const float*)d_in[8];
    const float* b2   = (const float*)d_in[9];
    float* out = (float*)d_out;

    const int N = in_sizes[0] / 64;           // 100000
    const int E = in_sizes[1];                // 1600000
    const int R = in_sizes[4] / (64 * 64);    // 8
    const int B = (N + 63) / 64;              // 1563 fine buckets

    // Workspace layout
    unsigned short* fstage = (unsigned short*)d_ws;            // [N][64] bf16 feat
    unsigned short* h1     = fstage + (size_t)N * 64;          // [N][64] bf16 relu(h1)
    unsigned short* Wt1    = h1 + (size_t)N * 64;              // [(R+1)*64*64]
    unsigned short* Wt2    = Wt1 + (size_t)(R + 1) * 64 * 64;  // [(R+1)*32*64]
    int* ghist   = (int*)(Wt2 + (size_t)(R + 1) * 32 * 64);    // [B]
    int* bstart  = ghist + B;                                  // [B+1]
    int* cursor  = bstart + (B + 1);                           // [B]
    int* brp     = cursor + B;                                 // [B*(R+1)]
    int* rec     = brp + (size_t)B * (R + 1);                  // [E]
    int* eidx    = rec + E;                                    // [E]

    const dim3 blk(256);
    const int P  = 128;                       // partition blocks
    const int CH = (E + P - 1) / P;           // 12500 edges per block
    const int n8 = N * 64 / 8;                // 800000

    // ---- Weight pre-transpose + input bf16 cast ----
    transpose_w<64><<<((R + 1) * 64 * 64 + 255) / 256, blk, 0, stream>>>(W1, Ws1, Wt1, R);
    transpose_w<32><<<((R + 1) * 32 * 64 + 255) / 256, blk, 0, stream>>>(W2, Ws2, Wt2, R);
    cast_bf16x8<<<(n8 + 255) / 256, blk, 0, stream>>>(feat, fstage, n8);

    // ---- Bucket partition + per-bucket relation sort ----
    zero_int<<<(B + 255) / 256, blk, 0, stream>>>(ghist, B);
    fine_hist<<<P, blk, 0, stream>>>(dst, ghist, E, B, CH);
    fine_scan<<<1, blk, 0, stream>>>(ghist, bstart, cursor, B, E);
    partition_fine<<<P, blk, 0, stream>>>(src, dst, et, cursor, rec, E, N, B, CH);
    bucket_sort_rel<<<B, blk, 0, stream>>>(bstart, rec, eidx, brp, R);

    // ---- Layer 1: fused aggregate+transform -> relu(h1) bf16 ----
    fused_layer<64, true><<<B, blk, 0, stream>>>(fstage, Wt1, b1, brp, eidx, h1, N, R);

    // ---- Layer 2: fused aggregate+transform -> out fp32 ----
    fused_layer<32, false><<<B, blk, 0, stream>>>(h1, Wt2, b2, brp, eidx, out, N, R);
}

// Round 2
// 391.343 us; speedup vs baseline: 3.6142x; 3.6142x over previous
//
#include <hip/hip_runtime.h>
#include <hip/hip_bf16.h>

typedef __attribute__((ext_vector_type(8))) short short8;
typedef __attribute__((ext_vector_type(4))) float f32x4;

__device__ __forceinline__ unsigned short f2bf(float v) {
    __hip_bfloat16 h = __float2bfloat16(v);   // RNE
    return *reinterpret_cast<unsigned short*>(&h);
}
__device__ __forceinline__ float bf2f(unsigned short u) {
    union { unsigned int i; float f; } x;
    x.i = (unsigned int)u << 16;
    return x.f;
}

constexpr int MAXB = 2048;   // max fine buckets (N/64 = 1563 here)

// ---------------------------------------------------------------------------
// Weight pre-transpose: Wt[(r*H + h)*64 + d] = bf16( r<R ? W[r][d][h]
//                                                        : Wself[d][h] ).
// ---------------------------------------------------------------------------
template<int H>
__global__ __launch_bounds__(256) void transpose_w(
    const float* __restrict__ W, const float* __restrict__ Wself,
    unsigned short* __restrict__ Wt, int R)
{
    int i = blockIdx.x * 256 + threadIdx.x;
    int total = (R + 1) * H * 64;
    if (i >= total) return;
    int d = i & 63;
    int hh = i >> 6;               // r*H + h
    int r = hh / H, h = hh % H;    // H compile-time -> shifts
    float v = (r < R) ? W[((size_t)r * 64 + d) * H + h]
                      : Wself[(size_t)d * H + h];
    Wt[i] = f2bf(v);
}

// ---------------------------------------------------------------------------
// MFMA relation GEMM (R10 structure: operand-swapped, depth-2 W prefetch).
// ABF: A input is bf16 (layer2, h1) vs fp32 (layer1, feat).
// SBF: self-loop output is bf16 (layer1 -> h1) vs fp32 (layer2 -> out).
// Epilogue (new): stage each relation tile in LDS, write out coalesced
// 16B/lane row-major stores (kills the 8B scattered-store amplification).
// ---------------------------------------------------------------------------
template<int H, int RT, bool ABF, bool SBF>
__global__ __launch_bounds__(512) void gemm_rel_mfma(
    const void* __restrict__ Av, const unsigned short* __restrict__ Wt,
    const float* __restrict__ bias,
    unsigned short* __restrict__ C, void* __restrict__ Cselfv,
    int N, int Rrt, int relu)
{
    constexpr int AS = 72;   // 144 B/row = 36 words = 4 mod 32 -> 2-way (free)
    constexpr int CPB = (H == 64) ? 72 : 40;   // bf16 staging stride (16B-aligned rows)
    __shared__ unsigned short As[64 * AS];
    alignas(16) __shared__ float Csf[64 * 36];  // 9216B staging (bf16/fp32 union)
    const int R = RT ? RT : Rrt;
    const int tid = threadIdx.x;
    const int n0 = blockIdx.x * 64;

    if constexpr (ABF) {
        // bf16 input: 64x64 = 4096 ushorts = exactly 512 short8 slots.
        const unsigned short* A = (const unsigned short*)Av;
        int n = tid >> 3, d8 = (tid & 7) * 8;
        int gn = n0 + n;
        short8 u = {};
        if (gn < N) u = *(const short8*)&A[(size_t)gn * 64 + d8];
        if (relu) {
            #pragma unroll
            for (int j = 0; j < 8; ++j) {
                unsigned short x = (unsigned short)u[j];
                u[j] = (short)((x & 0x8000) ? 0 : x);   // bf16 relu = sign test
            }
        }
        *(short8*)&As[n * AS + d8] = u;
    } else {
        const float* A = (const float*)Av;
        #pragma unroll
        for (int i = 0; i < 2; ++i) {
            int lin = tid + i * 512;
            int n = lin >> 4;
            int d4 = (lin & 15) * 4;
            int gn = n0 + n;
            float4 v = make_float4(0.f, 0.f, 0.f, 0.f);
            if (gn < N) v = *(const float4*)&A[(size_t)gn * 64 + d4];
            if (relu) {
                v.x = fmaxf(v.x, 0.f); v.y = fmaxf(v.y, 0.f);
                v.z = fmaxf(v.z, 0.f); v.w = fmaxf(v.w, 0.f);
            }
            ushort4 u;
            u.x = f2bf(v.x); u.y = f2bf(v.y); u.z = f2bf(v.z); u.w = f2bf(v.w);
            *(ushort4*)&As[n * AS + d4] = u;
        }
    }

    const int w = tid >> 6, lane = tid & 63;
    const int m = lane & 15, quad = lane >> 4;
    const int wt = w & 3;        // node sub-tile (16 nodes)
    const int half = w >> 2;     // column half (H/2 cols)

    __syncthreads();

    // Node fragment (B operand): B[k][n=lane&15] = feat[node][k].
    short8 afrag[2];
    afrag[0] = *(const short8*)&As[(wt * 16 + m) * AS + 0 * 32 + quad * 8];
    afrag[1] = *(const short8*)&As[(wt * 16 + m) * AS + 1 * 32 + quad * 8];

    constexpr int NT = H / 32;   // col-tiles per wave (64->2, 32->1)

    auto wptr = [&](int r, int nt, int kc) {
        int colbase = half * (H / 2) + nt * 16;
        return (const short8*)&Wt[((size_t)(r * H + colbase + m)) * 64 + kc * 32 + quad * 8];
    };

    short8 wf0[NT][2], wf1[NT][2];
    #pragma unroll
    for (int nt = 0; nt < NT; ++nt) { wf0[nt][0] = *wptr(0, nt, 0); wf0[nt][1] = *wptr(0, nt, 1); }
    #pragma unroll
    for (int nt = 0; nt < NT; ++nt) { wf1[nt][0] = *wptr(1, nt, 0); wf1[nt][1] = *wptr(1, nt, 1); }

    #pragma unroll
    for (int r = 0; r <= R; ++r) {
        short8 wn[NT][2];
        if (r + 2 <= R) {
            #pragma unroll
            for (int nt = 0; nt < NT; ++nt) {
                wn[nt][0] = *wptr(r + 2, nt, 0);
                wn[nt][1] = *wptr(r + 2, nt, 1);
            }
        }

        f32x4 acc[NT];
        #pragma unroll
        for (int nt = 0; nt < NT; ++nt) {
            acc[nt] = (f32x4){0.f, 0.f, 0.f, 0.f};
            acc[nt] = __builtin_amdgcn_mfma_f32_16x16x32_bf16(wf0[nt][0], afrag[0], acc[nt], 0, 0, 0);
            acc[nt] = __builtin_amdgcn_mfma_f32_16x16x32_bf16(wf0[nt][1], afrag[1], acc[nt], 0, 0, 0);
        }

        // D layout (swapped): reg i -> h-col = colbase + quad*4 + i, lane&15 -> node.
        __syncthreads();   // Csf free (previous relation's writeout reads done)
        if (r < R) {
            unsigned short* Cb = (unsigned short*)Csf;
            #pragma unroll
            for (int nt = 0; nt < NT; ++nt) {
                int col = half * (H / 2) + nt * 16 + quad * 4;
                ushort4 u;
                u.x = f2bf(acc[nt][0]); u.y = f2bf(acc[nt][1]);
                u.z = f2bf(acc[nt][2]); u.w = f2bf(acc[nt][3]);
                *(ushort4*)&Cb[(wt * 16 + m) * CPB + col] = u;
            }
            __syncthreads();
            if (H == 64) {
                int rw = tid >> 3, ch = tid & 7;      // 64 rows x 8 chunks of 16B
                int gn = n0 + rw;
                if (gn < N) {
                    uint4 v = *(const uint4*)&Cb[rw * CPB + ch * 8];
                    *(uint4*)&C[((size_t)r * N + gn) * H + ch * 8] = v;
                }
            } else {
                if (tid < 256) {
                    int rw = tid >> 2, ch = tid & 3;  // 64 rows x 4 chunks of 16B
                    int gn = n0 + rw;
                    if (gn < N) {
                        uint4 v = *(const uint4*)&Cb[rw * CPB + ch * 8];
                        *(uint4*)&C[((size_t)r * N + gn) * H + ch * 8] = v;
                    }
                }
            }
        } else if constexpr (SBF) {
            // self-loop + bias -> bf16 (layer 1 h1)
            unsigned short* Cb = (unsigned short*)Csf;
            #pragma unroll
            for (int nt = 0; nt < NT; ++nt) {
                int col = half * (H / 2) + nt * 16 + quad * 4;
                const float4 bv = *(const float4*)&bias[col];
                ushort4 u;
                u.x = f2bf(acc[nt][0] + bv.x); u.y = f2bf(acc[nt][1] + bv.y);
                u.z = f2bf(acc[nt][2] + bv.z); u.w = f2bf(acc[nt][3] + bv.w);
                *(ushort4*)&Cb[(wt * 16 + m) * CPB + col] = u;
            }
            __syncthreads();
            unsigned short* Cs = (unsigned short*)Cselfv;
            int rw = tid >> 3, ch = tid & 7;
            int gn = n0 + rw;
            if (gn < N) {
                uint4 v = *(const uint4*)&Cb[rw * CPB + ch * 8];
                *(uint4*)&Cs[(size_t)gn * H + ch * 8] = v;
            }
        } else {
            // self-loop + bias -> fp32 (layer 2 out), H==32
            float* Cf = Csf;
            #pragma unroll
            for (int nt = 0; nt < NT; ++nt) {
                int col = half * (H / 2) + nt * 16 + quad * 4;
                const float4 bv = *(const float4*)&bias[col];
                float4 o = make_float4(acc[nt][0] + bv.x, acc[nt][1] + bv.y,
                                       acc[nt][2] + bv.z, acc[nt][3] + bv.w);
                *(float4*)&Cf[(wt * 16 + m) * 36 + col] = o;
            }
            __syncthreads();
            float* outf = (float*)Cselfv;
            int rw = tid >> 3, ch = tid & 7;          // 64 rows x 8 float4
            int gn = n0 + rw;
            if (gn < N) {
                float4 v = *(const float4*)&Cf[rw * 36 + ch * 4];
                *(float4*)&outf[(size_t)gn * 32 + ch * 4] = v;
            }
        }

        #pragma unroll
        for (int nt = 0; nt < NT; ++nt) {
            wf0[nt][0] = wf1[nt][0]; wf0[nt][1] = wf1[nt][1];
            wf1[nt][0] = wn[nt][0];  wf1[nt][1] = wn[nt][1];
        }
    }
}

// ---------------------------------------------------------------------------
// Bucket partition. Bucket = 64 consecutive dst nodes.
// Record: (et*N + src) << 6 | (dst & 63).
// ---------------------------------------------------------------------------
__global__ __launch_bounds__(256) void zero_int(int* __restrict__ p, int n) {
    int i = blockIdx.x * 256 + threadIdx.x;
    if (i < n) p[i] = 0;
}

__global__ __launch_bounds__(256) void fine_hist(
    const int* __restrict__ dst, int* __restrict__ ghist, int E, int B, int CH)
{
    __shared__ int hist[MAXB];
    const int t = threadIdx.x;
    const int e0 = blockIdx.x * CH, e1 = min(E, e0 + CH);
    for (int i = t; i < B; i += 256) hist[i] = 0;
    __syncthreads();
    for (int e = e0 + t; e < e1; e += 256) atomicAdd(&hist[dst[e] >> 6], 1);
    __syncthreads();
    for (int i = t; i < B; i += 256) {
        int h = hist[i];
        if (h) atomicAdd(&ghist[i], h);
    }
}

__global__ __launch_bounds__(256) void fine_scan(
    const int* __restrict__ ghist, int* __restrict__ bstart,
    int* __restrict__ cursor, int B, int E)
{
    __shared__ int ts[256];
    const int t = threadIdx.x;
    const int PER = (B + 255) / 256;   // <= 8
    int loc[8];
    int s = 0;
    for (int j = 0; j < PER; ++j) {
        int i = t * PER + j;
        loc[j] = (i < B) ? ghist[i] : 0;
        s += loc[j];
    }
    ts[t] = s;
    __syncthreads();
    for (int off = 1; off < 256; off <<= 1) {
        int x = (t >= off) ? ts[t - off] : 0;
        __syncthreads();
        ts[t] += x;
        __syncthreads();
    }
    int run = ts[t] - s;
    for (int j = 0; j < PER; ++j) {
        int i = t * PER + j;
        if (i < B) { bstart[i] = run; cursor[i] = run; }
        run += loc[j];
    }
    if (t == 255) bstart[B] = E;
}

__global__ __launch_bounds__(256) void partition_fine(
    const int* __restrict__ src, const int* __restrict__ dst,
    const int* __restrict__ et, int* __restrict__ cursor,
    int* __restrict__ rec, int E, int N, int B, int CH)
{
    __shared__ int hist[MAXB];
    __shared__ int base[MAXB];
    __shared__ int cnt[MAXB];
    const int t = threadIdx.x;
    const int e0 = blockIdx.x * CH, e1 = min(E, e0 + CH);

    for (int i = t; i < B; i += 256) hist[i] = 0;
    __syncthreads();
    for (int e = e0 + t; e < e1; e += 256) atomicAdd(&hist[dst[e] >> 6], 1);
    __syncthreads();
    for (int i = t; i < B; i += 256) {
        int h = hist[i];
        base[i] = h ? atomicAdd(&cursor[i], h) : 0;
        cnt[i] = 0;
    }
    __syncthreads();
    for (int e = e0 + t; e < e1; e += 256) {
        int d = dst[e];
        int b = d >> 6;
        int pos = base[b] + atomicAdd(&cnt[b], 1);
        rec[pos] = ((et[e] * N + src[e]) << 6) | (d & 63);
    }
}

// ---------------------------------------------------------------------------
// Per-bucket counting sort -> per-node CSR (row_ptr + eidx).
// ---------------------------------------------------------------------------
__global__ __launch_bounds__(256) void bucket_sort(
    const int* __restrict__ bstart, const int* __restrict__ rec,
    int* __restrict__ eidx, int* __restrict__ row_ptr, int N, int E)
{
    __shared__ int hist[64];
    __shared__ int excl[64];
    __shared__ int cur[64];
    const int b = blockIdx.x;
    const int tid = threadIdx.x;
    const int p0 = bstart[b], p1 = bstart[b + 1];

    if (tid < 64) hist[tid] = 0;
    __syncthreads();
    for (int p = p0 + tid; p < p1; p += 256)
        atomicAdd(&hist[rec[p] & 63], 1);
    __syncthreads();
    if (tid == 0) {
        int run = 0;
        #pragma unroll
        for (int i = 0; i < 64; ++i) { excl[i] = run; run += hist[i]; }
    }
    __syncthreads();
    if (tid < 64) {
        cur[tid] = excl[tid];
        int n = b * 64 + tid;
        if (n < N) row_ptr[n] = p0 + excl[tid];
    }
    if (b == 0 && tid == 0) row_ptr[N] = E;
    __syncthreads();
    for (int p = p0 + tid; p < p1; p += 256) {
        int rv = rec[p];
        int pos = p0 + atomicAdd(&cur[rv & 63], 1);
        eidx[pos] = rv >> 6;   // et*N + src
    }
}

// ---------------------------------------------------------------------------
// agg64: one 64-lane wave per dst node. Lane loads a packed uint (2 bf16
// cols); the two 32-lane halves walk alternate edges (2-edge MLP + 4-deep
// unroll = 8 in flight). Combine via shfl; h1 is bf16 (packed uint I/O).
// ---------------------------------------------------------------------------
__global__ __launch_bounds__(256) void agg_csr64(
    const unsigned int* __restrict__ hw32, const int* __restrict__ row_ptr,
    const int* __restrict__ eidx, unsigned int* __restrict__ out32, int N)
{
    const int d = blockIdx.x * 4 + (threadIdx.x >> 6);
    const int lane = threadIdx.x & 63;
    if (d >= N) return;
    const int he = lane >> 5;     // which edge of each pair
    const int c = lane & 31;      // uint col (2 bf16 cols)
    const int p0 = row_ptr[d], p1 = row_ptr[d + 1];
    float s0 = 0.f, s1 = 0.f, t0 = 0.f, t1 = 0.f;
    int p = p0 + he;
    for (; p + 6 < p1; p += 8) {
        unsigned int v0 = hw32[(size_t)eidx[p]     * 32 + c];
        unsigned int v1 = hw32[(size_t)eidx[p + 2] * 32 + c];
        unsigned int v2 = hw32[(size_t)eidx[p + 4] * 32 + c];
        unsigned int v3 = hw32[(size_t)eidx[p + 6] * 32 + c];
        s0 += bf2f((unsigned short)(v0 & 0xffff)); s1 += bf2f((unsigned short)(v0 >> 16));
        t0 += bf2f((unsigned short)(v1 & 0xffff)); t1 += bf2f((unsigned short)(v1 >> 16));
        s0 += bf2f((unsigned short)(v2 & 0xffff)); s1 += bf2f((unsigned short)(v2 >> 16));
        t0 += bf2f((unsigned short)(v3 & 0xffff)); t1 += bf2f((unsigned short)(v3 >> 16));
    }
    for (; p < p1; p += 2) {
        unsigned int v = hw32[(size_t)eidx[p] * 32 + c];
        s0 += bf2f((unsigned short)(v & 0xffff)); s1 += bf2f((unsigned short)(v >> 16));
    }
    s0 += t0; s1 += t1;
    float u0 = __shfl(s0, c + 32, 64);   // partner in upper half
    float u1 = __shfl(s1, c + 32, 64);
    if (he == 0) {
        unsigned int cur = out32[(size_t)d * 32 + c];
        float o0 = s0 + u0 + bf2f((unsigned short)(cur & 0xffff));
        float o1 = s1 + u1 + bf2f((unsigned short)(cur >> 16));
        out32[(size_t)d * 32 + c] = (unsigned int)f2bf(o0) | ((unsigned int)f2bf(o1) << 16);
    }
}

// ---------------------------------------------------------------------------
// agg32: 32 lanes per dst node (8 nodes/block); 16-lane halves walk alternate
// edges with packed-uint loads; combine via shfl; out is fp32 (d_out).
// ---------------------------------------------------------------------------
__global__ __launch_bounds__(256) void agg_csr32(
    const unsigned int* __restrict__ hw32, const int* __restrict__ row_ptr,
    const int* __restrict__ eidx, float* __restrict__ out, int N)
{
    const int d = blockIdx.x * 8 + (threadIdx.x >> 5);
    const int l = threadIdx.x & 31;
    if (d >= N) return;
    const int he = l >> 4;
    const int c = l & 15;         // uint col (2 bf16 cols of 32)
    const int p0 = row_ptr[d], p1 = row_ptr[d + 1];
    float s0 = 0.f, s1 = 0.f, t0 = 0.f, t1 = 0.f;
    int p = p0 + he;
    for (; p + 6 < p1; p += 8) {
        unsigned int v0 = hw32[(size_t)eidx[p]     * 16 + c];
        unsigned int v1 = hw32[(size_t)eidx[p + 2] * 16 + c];
        unsigned int v2 = hw32[(size_t)eidx[p + 4] * 16 + c];
        unsigned int v3 = hw32[(size_t)eidx[p + 6] * 16 + c];
        s0 += bf2f((unsigned short)(v0 & 0xffff)); s1 += bf2f((unsigned short)(v0 >> 16));
        t0 += bf2f((unsigned short)(v1 & 0xffff)); t1 += bf2f((unsigned short)(v1 >> 16));
        s0 += bf2f((unsigned short)(v2 & 0xffff)); s1 += bf2f((unsigned short)(v2 >> 16));
        t0 += bf2f((unsigned short)(v3 & 0xffff)); t1 += bf2f((unsigned short)(v3 >> 16));
    }
    for (; p < p1; p += 2) {
        unsigned int v = hw32[(size_t)eidx[p] * 16 + c];
        s0 += bf2f((unsigned short)(v & 0xffff)); s1 += bf2f((unsigned short)(v >> 16));
    }
    s0 += t0; s1 += t1;
    float u0 = __shfl(s0, (threadIdx.x & 63) ^ 16, 64);
    float u1 = __shfl(s1, (threadIdx.x & 63) ^ 16, 64);
    if (he == 0) {
        float2 cur = *(const float2*)&out[(size_t)d * 32 + c * 2];
        float2 o = make_float2(cur.x + s0 + u0, cur.y + s1 + u1);
        *(float2*)&out[(size_t)d * 32 + c * 2] = o;
    }
}

extern "C" void kernel_launch(void* const* d_in, const int* in_sizes, int n_in,
                              void* d_out, int out_size, void* d_ws, size_t ws_size,
                              hipStream_t stream)
{
    const float* feat = (const float*)d_in[0];
    const int*   src  = (const int*)d_in[1];
    const int*   dst  = (const int*)d_in[2];
    const int*   et   = (const int*)d_in[3];
    const float* W1   = (const float*)d_in[4];
    const float* Ws1  = (const float*)d_in[5];
    const float* b1   = (const float*)d_in[6];
    const float* W2   = (const float*)d_in[7];
    const float* Ws2  = (const float*)d_in[8];
    const float* b2   = (const float*)d_in[9];
    float* out = (float*)d_out;

    const int N = in_sizes[0] / 64;           // 100000
    const int E = in_sizes[1];                // 1600000
    const int R = in_sizes[4] / (64 * 64);    // 8
    const int B = (N + 63) / 64;              // 1563 fine buckets

    // Workspace layout
    unsigned short* hW  = (unsigned short*)d_ws;           // [R][N][64] bf16 (reused [R][N][32])
    unsigned short* h1  = hW + (size_t)R * N * 64;         // [N][64] bf16
    unsigned short* Wt1 = h1 + (size_t)N * 64;             // [(R+1)*64*64]
    unsigned short* Wt2 = Wt1 + (size_t)(R + 1) * 64 * 64; // [(R+1)*32*64]
    int*   ghist   = (int*)(Wt2 + (size_t)(R + 1) * 32 * 64);  // [B]
    int*   bstart  = ghist + B;                            // [B+1]
    int*   cursor  = bstart + (B + 1);                     // [B]
    int*   row_ptr = cursor + B;                           // [N+1]
    int*   rec     = row_ptr + (N + 1);                    // [E]
    int*   eidx    = rec + E;                              // [E]

    const dim3 blk(256);
    const int nblk64 = (N + 63) / 64;
    const int P  = 128;                       // partition blocks
    const int CH = (E + P - 1) / P;           // 12500 edges per block

    // ---- Weight pre-transpose (bf16, [r][h][d]) ----
    transpose_w<64><<<((R + 1) * 64 * 64 + 255) / 256, blk, 0, stream>>>(W1, Ws1, Wt1, R);
    transpose_w<32><<<((R + 1) * 32 * 64 + 255) / 256, blk, 0, stream>>>(W2, Ws2, Wt2, R);

    // ---- Build per-node CSR via bucket partition + per-bucket sort ----
    zero_int<<<(B + 255) / 256, blk, 0, stream>>>(ghist, B);
    fine_hist<<<P, blk, 0, stream>>>(dst, ghist, E, B, CH);
    fine_scan<<<1, blk, 0, stream>>>(ghist, bstart, cursor, B, E);
    partition_fine<<<P, blk, 0, stream>>>(src, dst, et, cursor, rec, E, N, B, CH);
    bucket_sort<<<B, blk, 0, stream>>>(bstart, rec, eidx, row_ptr, N, E);

    // ---- Layer 1 ---- (hW1 bf16 + self-loop bf16 into h1, fused)
    if (R == 8)
        gemm_rel_mfma<64, 8, false, true><<<nblk64, 512, 0, stream>>>(feat, Wt1, b1, hW, h1, N, R, 0);
    else
        gemm_rel_mfma<64, 0, false, true><<<nblk64, 512, 0, stream>>>(feat, Wt1, b1, hW, h1, N, R, 0);
    agg_csr64<<<dim3((N + 3) / 4), blk, 0, stream>>>((const unsigned int*)hW, row_ptr, eidx,
                                                     (unsigned int*)h1, N);

    // ---- Layer 2 ---- (bf16 A staging with bit-mask ReLU; self fp32 -> out)
    if (R == 8)
        gemm_rel_mfma<32, 8, true, false><<<nblk64, 512, 0, stream>>>(h1, Wt2, b2, hW, out, N, R, 1);
    else
        gemm_rel_mfma<32, 0, true, false><<<nblk64, 512, 0, stream>>>(h1, Wt2, b2, hW, out, N, R, 1);
    agg_csr32<<<dim3((N + 7) / 8), blk, 0, stream>>>((const unsigned int*)hW, row_ptr, eidx, out, N);
}

// Round 3
// 377.065 us; speedup vs baseline: 3.7511x; 1.0379x over previous
//
#include <hip/hip_runtime.h>
#include <hip/hip_bf16.h>

typedef __attribute__((ext_vector_type(8))) short short8;
typedef __attribute__((ext_vector_type(4))) float f32x4;

__device__ __forceinline__ unsigned short f2bf(float v) {
    __hip_bfloat16 h = __float2bfloat16(v);   // RNE
    return *reinterpret_cast<unsigned short*>(&h);
}
__device__ __forceinline__ float bf2f(unsigned short u) {
    union { unsigned int i; float f; } x;
    x.i = (unsigned int)u << 16;
    return x.f;
}

constexpr int MAXB = 2048;   // max fine buckets (N/64 = 1563 here)

// ---------------------------------------------------------------------------
// Weight pre-transpose: Wt[(r*H + h)*64 + d] = bf16( r<R ? W[r][d][h]
//                                                        : Wself[d][h] ).
// ---------------------------------------------------------------------------
template<int H>
__global__ __launch_bounds__(256) void transpose_w(
    const float* __restrict__ W, const float* __restrict__ Wself,
    unsigned short* __restrict__ Wt, int R)
{
    int i = blockIdx.x * 256 + threadIdx.x;
    int total = (R + 1) * H * 64;
    if (i >= total) return;
    int d = i & 63;
    int hh = i >> 6;               // r*H + h
    int r = hh / H, h = hh % H;    // H compile-time -> shifts
    float v = (r < R) ? W[((size_t)r * 64 + d) * H + h]
                      : Wself[(size_t)d * H + h];
    Wt[i] = f2bf(v);
}

// ---------------------------------------------------------------------------
// MFMA relation GEMM (operand-swapped, depth-2 W prefetch).
// ABF: A input is bf16 (layer2, h1) vs fp32 (layer1, feat).
// SBF: self-loop output is bf16 (layer1 -> h1) vs fp32 (layer2 -> out).
// Epilogue: stage each relation tile in a DOUBLE-BUFFERED LDS tile, write out
// coalesced 16B/lane row-major stores. One barrier per relation (buffer r&1
// is reused at r+2; the barrier at r+1 drains the r readout's lgkmcnt).
// ---------------------------------------------------------------------------
template<int H, int RT, bool ABF, bool SBF>
__global__ __launch_bounds__(512) void gemm_rel_mfma(
    const void* __restrict__ Av, const unsigned short* __restrict__ Wt,
    const float* __restrict__ bias,
    unsigned short* __restrict__ C, void* __restrict__ Cselfv,
    int N, int Rrt, int relu)
{
    constexpr int AS = 72;   // 144 B/row = 36 words = 4 mod 32 -> 2-way (free)
    constexpr int CPB = (H == 64) ? 72 : 40;   // bf16 staging stride (16B-aligned rows)
    __shared__ unsigned short As[64 * AS];
    alignas(16) __shared__ float Csf[2][64 * 36];  // dbuf staging (bf16/fp32 union)
    const int R = RT ? RT : Rrt;
    const int tid = threadIdx.x;
    const int n0 = blockIdx.x * 64;

    if constexpr (ABF) {
        // bf16 input: 64x64 = 4096 ushorts = exactly 512 short8 slots.
        const unsigned short* A = (const unsigned short*)Av;
        int n = tid >> 3, d8 = (tid & 7) * 8;
        int gn = n0 + n;
        short8 u = {};
        if (gn < N) u = *(const short8*)&A[(size_t)gn * 64 + d8];
        if (relu) {
            #pragma unroll
            for (int j = 0; j < 8; ++j) {
                unsigned short x = (unsigned short)u[j];
                u[j] = (short)((x & 0x8000) ? 0 : x);   // bf16 relu = sign test
            }
        }
        *(short8*)&As[n * AS + d8] = u;
    } else {
        const float* A = (const float*)Av;
        #pragma unroll
        for (int i = 0; i < 2; ++i) {
            int lin = tid + i * 512;
            int n = lin >> 4;
            int d4 = (lin & 15) * 4;
            int gn = n0 + n;
            float4 v = make_float4(0.f, 0.f, 0.f, 0.f);
            if (gn < N) v = *(const float4*)&A[(size_t)gn * 64 + d4];
            if (relu) {
                v.x = fmaxf(v.x, 0.f); v.y = fmaxf(v.y, 0.f);
                v.z = fmaxf(v.z, 0.f); v.w = fmaxf(v.w, 0.f);
            }
            ushort4 u;
            u.x = f2bf(v.x); u.y = f2bf(v.y); u.z = f2bf(v.z); u.w = f2bf(v.w);
            *(ushort4*)&As[n * AS + d4] = u;
        }
    }

    const int w = tid >> 6, lane = tid & 63;
    const int m = lane & 15, quad = lane >> 4;
    const int wt = w & 3;        // node sub-tile (16 nodes)
    const int half = w >> 2;     // column half (H/2 cols)

    __syncthreads();

    // Node fragment (B operand): B[k][n=lane&15] = feat[node][k].
    short8 afrag[2];
    afrag[0] = *(const short8*)&As[(wt * 16 + m) * AS + 0 * 32 + quad * 8];
    afrag[1] = *(const short8*)&As[(wt * 16 + m) * AS + 1 * 32 + quad * 8];

    constexpr int NT = H / 32;   // col-tiles per wave (64->2, 32->1)

    auto wptr = [&](int r, int nt, int kc) {
        int colbase = half * (H / 2) + nt * 16;
        return (const short8*)&Wt[((size_t)(r * H + colbase + m)) * 64 + kc * 32 + quad * 8];
    };

    short8 wf0[NT][2], wf1[NT][2];
    #pragma unroll
    for (int nt = 0; nt < NT; ++nt) { wf0[nt][0] = *wptr(0, nt, 0); wf0[nt][1] = *wptr(0, nt, 1); }
    #pragma unroll
    for (int nt = 0; nt < NT; ++nt) { wf1[nt][0] = *wptr(1, nt, 0); wf1[nt][1] = *wptr(1, nt, 1); }

    #pragma unroll
    for (int r = 0; r <= R; ++r) {
        short8 wn[NT][2];
        if (r + 2 <= R) {
            #pragma unroll
            for (int nt = 0; nt < NT; ++nt) {
                wn[nt][0] = *wptr(r + 2, nt, 0);
                wn[nt][1] = *wptr(r + 2, nt, 1);
            }
        }

        f32x4 acc[NT];
        #pragma unroll
        for (int nt = 0; nt < NT; ++nt) {
            acc[nt] = (f32x4){0.f, 0.f, 0.f, 0.f};
            acc[nt] = __builtin_amdgcn_mfma_f32_16x16x32_bf16(wf0[nt][0], afrag[0], acc[nt], 0, 0, 0);
            acc[nt] = __builtin_amdgcn_mfma_f32_16x16x32_bf16(wf0[nt][1], afrag[1], acc[nt], 0, 0, 0);
        }

        // ---- stage into Csf[r&1] ----
        // D layout (swapped): reg i -> h-col = colbase + quad*4 + i, lane&15 -> node.
        unsigned short* Cb = (unsigned short*)Csf[r & 1];
        float* Cf = Csf[r & 1];
        if (r < R) {
            #pragma unroll
            for (int nt = 0; nt < NT; ++nt) {
                int col = half * (H / 2) + nt * 16 + quad * 4;
                ushort4 u;
                u.x = f2bf(acc[nt][0]); u.y = f2bf(acc[nt][1]);
                u.z = f2bf(acc[nt][2]); u.w = f2bf(acc[nt][3]);
                *(ushort4*)&Cb[(wt * 16 + m) * CPB + col] = u;
            }
        } else if constexpr (SBF) {
            #pragma unroll
            for (int nt = 0; nt < NT; ++nt) {
                int col = half * (H / 2) + nt * 16 + quad * 4;
                const float4 bv = *(const float4*)&bias[col];
                ushort4 u;
                u.x = f2bf(acc[nt][0] + bv.x); u.y = f2bf(acc[nt][1] + bv.y);
                u.z = f2bf(acc[nt][2] + bv.z); u.w = f2bf(acc[nt][3] + bv.w);
                *(ushort4*)&Cb[(wt * 16 + m) * CPB + col] = u;
            }
        } else {
            #pragma unroll
            for (int nt = 0; nt < NT; ++nt) {
                int col = half * (H / 2) + nt * 16 + quad * 4;
                const float4 bv = *(const float4*)&bias[col];
                float4 o = make_float4(acc[nt][0] + bv.x, acc[nt][1] + bv.y,
                                       acc[nt][2] + bv.z, acc[nt][3] + bv.w);
                *(float4*)&Cf[(wt * 16 + m) * 36 + col] = o;
            }
        }

        __syncthreads();   // single barrier per relation

        // ---- coalesced readout from Csf[r&1] ----
        if (r < R) {
            if (H == 64) {
                int rw = tid >> 3, ch = tid & 7;      // 64 rows x 8 chunks of 16B
                int gn = n0 + rw;
                if (gn < N) {
                    uint4 v = *(const uint4*)&Cb[rw * CPB + ch * 8];
                    *(uint4*)&C[((size_t)r * N + gn) * H + ch * 8] = v;
                }
            } else {
                if (tid < 256) {
                    int rw = tid >> 2, ch = tid & 3;  // 64 rows x 4 chunks of 16B
                    int gn = n0 + rw;
                    if (gn < N) {
                        uint4 v = *(const uint4*)&Cb[rw * CPB + ch * 8];
                        *(uint4*)&C[((size_t)r * N + gn) * H + ch * 8] = v;
                    }
                }
            }
        } else if constexpr (SBF) {
            unsigned short* Cs = (unsigned short*)Cselfv;
            int rw = tid >> 3, ch = tid & 7;
            int gn = n0 + rw;
            if (gn < N) {
                uint4 v = *(const uint4*)&Cb[rw * CPB + ch * 8];
                *(uint4*)&Cs[(size_t)gn * H + ch * 8] = v;
            }
        } else {
            float* outf = (float*)Cselfv;
            int rw = tid >> 3, ch = tid & 7;          // 64 rows x 8 float4
            int gn = n0 + rw;
            if (gn < N) {
                float4 v = *(const float4*)&Cf[rw * 36 + ch * 4];
                *(float4*)&outf[(size_t)gn * 32 + ch * 4] = v;
            }
        }

        #pragma unroll
        for (int nt = 0; nt < NT; ++nt) {
            wf0[nt][0] = wf1[nt][0]; wf0[nt][1] = wf1[nt][1];
            wf1[nt][0] = wn[nt][0];  wf1[nt][1] = wn[nt][1];
        }
    }
}

// ---------------------------------------------------------------------------
// Bucket partition. Bucket = 64 consecutive dst nodes.
// Record: (et*N + src) << 6 | (dst & 63).
// ---------------------------------------------------------------------------
__global__ __launch_bounds__(256) void zero_int(int* __restrict__ p, int n) {
    int i = blockIdx.x * 256 + threadIdx.x;
    if (i < n) p[i] = 0;
}

__global__ __launch_bounds__(256) void fine_hist(
    const int* __restrict__ dst, int* __restrict__ ghist, int E, int B, int CH)
{
    __shared__ int hist[MAXB];
    const int t = threadIdx.x;
    const int e0 = blockIdx.x * CH, e1 = min(E, e0 + CH);
    for (int i = t; i < B; i += 256) hist[i] = 0;
    __syncthreads();
    for (int e = e0 + t; e < e1; e += 256) atomicAdd(&hist[dst[e] >> 6], 1);
    __syncthreads();
    for (int i = t; i < B; i += 256) {
        int h = hist[i];
        if (h) atomicAdd(&ghist[i], h);
    }
}

__global__ __launch_bounds__(256) void fine_scan(
    const int* __restrict__ ghist, int* __restrict__ bstart,
    int* __restrict__ cursor, int B, int E)
{
    __shared__ int ts[256];
    const int t = threadIdx.x;
    const int PER = (B + 255) / 256;   // <= 8
    int loc[8];
    int s = 0;
    for (int j = 0; j < PER; ++j) {
        int i = t * PER + j;
        loc[j] = (i < B) ? ghist[i] : 0;
        s += loc[j];
    }
    ts[t] = s;
    __syncthreads();
    for (int off = 1; off < 256; off <<= 1) {
        int x = (t >= off) ? ts[t - off] : 0;
        __syncthreads();
        ts[t] += x;
        __syncthreads();
    }
    int run = ts[t] - s;
    for (int j = 0; j < PER; ++j) {
        int i = t * PER + j;
        if (i < B) { bstart[i] = run; cursor[i] = run; }
        run += loc[j];
    }
    if (t == 255) bstart[B] = E;
}

__global__ __launch_bounds__(256) void partition_fine(
    const int* __restrict__ src, const int* __restrict__ dst,
    const int* __restrict__ et, int* __restrict__ cursor,
    int* __restrict__ rec, int E, int N, int B, int CH)
{
    __shared__ int hist[MAXB];
    __shared__ int base[MAXB];
    __shared__ int cnt[MAXB];
    const int t = threadIdx.x;
    const int e0 = blockIdx.x * CH, e1 = min(E, e0 + CH);

    for (int i = t; i < B; i += 256) hist[i] = 0;
    __syncthreads();
    for (int e = e0 + t; e < e1; e += 256) atomicAdd(&hist[dst[e] >> 6], 1);
    __syncthreads();
    for (int i = t; i < B; i += 256) {
        int h = hist[i];
        base[i] = h ? atomicAdd(&cursor[i], h) : 0;
        cnt[i] = 0;
    }
    __syncthreads();
    for (int e = e0 + t; e < e1; e += 256) {
        int d = dst[e];
        int b = d >> 6;
        int pos = base[b] + atomicAdd(&cnt[b], 1);
        rec[pos] = ((et[e] * N + src[e]) << 6) | (d & 63);
    }
}

// ---------------------------------------------------------------------------
// Per-bucket counting sort -> per-node CSR (row_ptr + eidx).
// ---------------------------------------------------------------------------
__global__ __launch_bounds__(256) void bucket_sort(
    const int* __restrict__ bstart, const int* __restrict__ rec,
    int* __restrict__ eidx, int* __restrict__ row_ptr, int N, int E)
{
    __shared__ int hist[64];
    __shared__ int excl[64];
    __shared__ int cur[64];
    const int b = blockIdx.x;
    const int tid = threadIdx.x;
    const int p0 = bstart[b], p1 = bstart[b + 1];

    if (tid < 64) hist[tid] = 0;
    __syncthreads();
    for (int p = p0 + tid; p < p1; p += 256)
        atomicAdd(&hist[rec[p] & 63], 1);
    __syncthreads();
    if (tid == 0) {
        int run = 0;
        #pragma unroll
        for (int i = 0; i < 64; ++i) { excl[i] = run; run += hist[i]; }
    }
    __syncthreads();
    if (tid < 64) {
        cur[tid] = excl[tid];
        int n = b * 64 + tid;
        if (n < N) row_ptr[n] = p0 + excl[tid];
    }
    if (b == 0 && tid == 0) row_ptr[N] = E;
    __syncthreads();
    for (int p = p0 + tid; p < p1; p += 256) {
        int rv = rec[p];
        int pos = p0 + atomicAdd(&cur[rv & 63], 1);
        eidx[pos] = rv >> 6;   // et*N + src
    }
}

// ---------------------------------------------------------------------------
// agg64: one 64-lane wave per dst node. Lane loads a packed uint (2 bf16
// cols); the two 32-lane halves walk alternate edges (2-edge MLP + 4-deep
// unroll = 8 in flight). Combine via shfl; h1 is bf16 (packed uint I/O).
// ---------------------------------------------------------------------------
__global__ __launch_bounds__(256) void agg_csr64(
    const unsigned int* __restrict__ hw32, const int* __restrict__ row_ptr,
    const int* __restrict__ eidx, unsigned int* __restrict__ out32, int N)
{
    const int d = blockIdx.x * 4 + (threadIdx.x >> 6);
    const int lane = threadIdx.x & 63;
    if (d >= N) return;
    const int he = lane >> 5;     // which edge of each pair
    const int c = lane & 31;      // uint col (2 bf16 cols)
    const int p0 = row_ptr[d], p1 = row_ptr[d + 1];
    float s0 = 0.f, s1 = 0.f, t0 = 0.f, t1 = 0.f;
    int p = p0 + he;
    for (; p + 6 < p1; p += 8) {
        unsigned int v0 = hw32[(size_t)eidx[p]     * 32 + c];
        unsigned int v1 = hw32[(size_t)eidx[p + 2] * 32 + c];
        unsigned int v2 = hw32[(size_t)eidx[p + 4] * 32 + c];
        unsigned int v3 = hw32[(size_t)eidx[p + 6] * 32 + c];
        s0 += bf2f((unsigned short)(v0 & 0xffff)); s1 += bf2f((unsigned short)(v0 >> 16));
        t0 += bf2f((unsigned short)(v1 & 0xffff)); t1 += bf2f((unsigned short)(v1 >> 16));
        s0 += bf2f((unsigned short)(v2 & 0xffff)); s1 += bf2f((unsigned short)(v2 >> 16));
        t0 += bf2f((unsigned short)(v3 & 0xffff)); t1 += bf2f((unsigned short)(v3 >> 16));
    }
    for (; p < p1; p += 2) {
        unsigned int v = hw32[(size_t)eidx[p] * 32 + c];
        s0 += bf2f((unsigned short)(v & 0xffff)); s1 += bf2f((unsigned short)(v >> 16));
    }
    s0 += t0; s1 += t1;
    float u0 = __shfl(s0, c + 32, 64);   // partner in upper half
    float u1 = __shfl(s1, c + 32, 64);
    if (he == 0) {
        unsigned int cur = out32[(size_t)d * 32 + c];
        float o0 = s0 + u0 + bf2f((unsigned short)(cur & 0xffff));
        float o1 = s1 + u1 + bf2f((unsigned short)(cur >> 16));
        out32[(size_t)d * 32 + c] = (unsigned int)f2bf(o0) | ((unsigned int)f2bf(o1) << 16);
    }
}

// ---------------------------------------------------------------------------
// agg32: 32 lanes per dst node (8 nodes/block); 16-lane halves walk alternate
// edges with packed-uint loads; combine via shfl; out is fp32 (d_out).
// ---------------------------------------------------------------------------
__global__ __launch_bounds__(256) void agg_csr32(
    const unsigned int* __restrict__ hw32, const int* __restrict__ row_ptr,
    const int* __restrict__ eidx, float* __restrict__ out, int N)
{
    const int d = blockIdx.x * 8 + (threadIdx.x >> 5);
    const int l = threadIdx.x & 31;
    if (d >= N) return;
    const int he = l >> 4;
    const int c = l & 15;         // uint col (2 bf16 cols of 32)
    const int p0 = row_ptr[d], p1 = row_ptr[d + 1];
    float s0 = 0.f, s1 = 0.f, t0 = 0.f, t1 = 0.f;
    int p = p0 + he;
    for (; p + 6 < p1; p += 8) {
        unsigned int v0 = hw32[(size_t)eidx[p]     * 16 + c];
        unsigned int v1 = hw32[(size_t)eidx[p + 2] * 16 + c];
        unsigned int v2 = hw32[(size_t)eidx[p + 4] * 16 + c];
        unsigned int v3 = hw32[(size_t)eidx[p + 6] * 16 + c];
        s0 += bf2f((unsigned short)(v0 & 0xffff)); s1 += bf2f((unsigned short)(v0 >> 16));
        t0 += bf2f((unsigned short)(v1 & 0xffff)); t1 += bf2f((unsigned short)(v1 >> 16));
        s0 += bf2f((unsigned short)(v2 & 0xffff)); s1 += bf2f((unsigned short)(v2 >> 16));
        t0 += bf2f((unsigned short)(v3 & 0xffff)); t1 += bf2f((unsigned short)(v3 >> 16));
    }
    for (; p < p1; p += 2) {
        unsigned int v = hw32[(size_t)eidx[p] * 16 + c];
        s0 += bf2f((unsigned short)(v & 0xffff)); s1 += bf2f((unsigned short)(v >> 16));
    }
    s0 += t0; s1 += t1;
    float u0 = __shfl(s0, (threadIdx.x & 63) ^ 16, 64);
    float u1 = __shfl(s1, (threadIdx.x & 63) ^ 16, 64);
    if (he == 0) {
        float2 cur = *(const float2*)&out[(size_t)d * 32 + c * 2];
        float2 o = make_float2(cur.x + s0 + u0, cur.y + s1 + u1);
        *(float2*)&out[(size_t)d * 32 + c * 2] = o;
    }
}

extern "C" void kernel_launch(void* const* d_in, const int* in_sizes, int n_in,
                              void* d_out, int out_size, void* d_ws, size_t ws_size,
                              hipStream_t stream)
{
    const float* feat = (const float*)d_in[0];
    const int*   src  = (const int*)d_in[1];
    const int*   dst  = (const int*)d_in[2];
    const int*   et   = (const int*)d_in[3];
    const float* W1   = (const float*)d_in[4];
    const float* Ws1  = (const float*)d_in[5];
    const float* b1   = (const float*)d_in[6];
    const float* W2   = (const float*)d_in[7];
    const float* Ws2  = (const float*)d_in[8];
    const float* b2   = (const float*)d_in[9];
    float* out = (float*)d_out;

    const int N = in_sizes[0] / 64;           // 100000
    const int E = in_sizes[1];                // 1600000
    const int R = in_sizes[4] / (64 * 64);    // 8
    const int B = (N + 63) / 64;              // 1563 fine buckets

    // Workspace layout
    unsigned short* hW  = (unsigned short*)d_ws;           // [R][N][64] bf16 (reused [R][N][32])
    unsigned short* h1  = hW + (size_t)R * N * 64;         // [N][64] bf16
    unsigned short* Wt1 = h1 + (size_t)N * 64;             // [(R+1)*64*64]
    unsigned short* Wt2 = Wt1 + (size_t)(R + 1) * 64 * 64; // [(R+1)*32*64]
    int*   ghist   = (int*)(Wt2 + (size_t)(R + 1) * 32 * 64);  // [B]
    int*   bstart  = ghist + B;                            // [B+1]
    int*   cursor  = bstart + (B + 1);                     // [B]
    int*   row_ptr = cursor + B;                           // [N+1]
    int*   rec     = row_ptr + (N + 1);                    // [E]
    int*   eidx    = rec + E;                              // [E]

    const dim3 blk(256);
    const int nblk64 = (N + 63) / 64;
    const int P  = 512;                       // partition blocks (was 128: 2 waves/CU)
    const int CH = (E + P - 1) / P;           // 3125 edges per block

    // ---- Weight pre-transpose (bf16, [r][h][d]) ----
    transpose_w<64><<<((R + 1) * 64 * 64 + 255) / 256, blk, 0, stream>>>(W1, Ws1, Wt1, R);
    transpose_w<32><<<((R + 1) * 32 * 64 + 255) / 256, blk, 0, stream>>>(W2, Ws2, Wt2, R);

    // ---- Build per-node CSR via bucket partition + per-bucket sort ----
    zero_int<<<(B + 255) / 256, blk, 0, stream>>>(ghist, B);
    fine_hist<<<P, blk, 0, stream>>>(dst, ghist, E, B, CH);
    fine_scan<<<1, blk, 0, stream>>>(ghist, bstart, cursor, B, E);
    partition_fine<<<P, blk, 0, stream>>>(src, dst, et, cursor, rec, E, N, B, CH);
    bucket_sort<<<B, blk, 0, stream>>>(bstart, rec, eidx, row_ptr, N, E);

    // ---- Layer 1 ---- (hW1 bf16 + self-loop bf16 into h1, fused)
    if (R == 8)
        gemm_rel_mfma<64, 8, false, true><<<nblk64, 512, 0, stream>>>(feat, Wt1, b1, hW, h1, N, R, 0);
    else
        gemm_rel_mfma<64, 0, false, true><<<nblk64, 512, 0, stream>>>(feat, Wt1, b1, hW, h1, N, R, 0);
    agg_csr64<<<dim3((N + 3) / 4), blk, 0, stream>>>((const unsigned int*)hW, row_ptr, eidx,
                                                     (unsigned int*)h1, N);

    // ---- Layer 2 ---- (bf16 A staging with bit-mask ReLU; self fp32 -> out)
    if (R == 8)
        gemm_rel_mfma<32, 8, true, false><<<nblk64, 512, 0, stream>>>(h1, Wt2, b2, hW, out, N, R, 1);
    else
        gemm_rel_mfma<32, 0, true, false><<<nblk64, 512, 0, stream>>>(h1, Wt2, b2, hW, out, N, R, 1);
    agg_csr32<<<dim3((N + 7) / 8), blk, 0, stream>>>((const unsigned int*)hW, row_ptr, eidx, out, N);
}

// Round 4
// 375.622 us; speedup vs baseline: 3.7655x; 1.0038x over previous
//
#include <hip/hip_runtime.h>
#include <hip/hip_bf16.h>

typedef __attribute__((ext_vector_type(8))) short short8;
typedef __attribute__((ext_vector_type(4))) float f32x4;

__device__ __forceinline__ unsigned short f2bf(float v) {
    __hip_bfloat16 h = __float2bfloat16(v);   // RNE
    return *reinterpret_cast<unsigned short*>(&h);
}
__device__ __forceinline__ float bf2f(unsigned short u) {
    union { unsigned int i; float f; } x;
    x.i = (unsigned int)u << 16;
    return x.f;
}

// Cross-wave LDS barrier WITHOUT the vmcnt(0) drain __syncthreads carries.
// Orders ds_write -> (all waves) -> ds_read; leaves global stores in flight.
__device__ __forceinline__ void lds_barrier() {
    asm volatile("s_waitcnt lgkmcnt(0)" ::: "memory");
    __builtin_amdgcn_s_barrier();
    asm volatile("" ::: "memory");
}

constexpr int MAXB = 2048;   // max fine buckets (N/64 = 1563 here)

// ---------------------------------------------------------------------------
// Weight pre-transpose: Wt[(r*H + h)*64 + d] = bf16( r<R ? W[r][d][h]
//                                                        : Wself[d][h] ).
// ---------------------------------------------------------------------------
template<int H>
__global__ __launch_bounds__(256) void transpose_w(
    const float* __restrict__ W, const float* __restrict__ Wself,
    unsigned short* __restrict__ Wt, int R)
{
    int i = blockIdx.x * 256 + threadIdx.x;
    int total = (R + 1) * H * 64;
    if (i >= total) return;
    int d = i & 63;
    int hh = i >> 6;               // r*H + h
    int r = hh / H, h = hh % H;    // H compile-time -> shifts
    float v = (r < R) ? W[((size_t)r * 64 + d) * H + h]
                      : Wself[(size_t)d * H + h];
    Wt[i] = f2bf(v);
}

// ---------------------------------------------------------------------------
// MFMA relation GEMM (operand-swapped, depth-2 W prefetch).
// ABF: A input is bf16 (layer2, h1) vs fp32 (layer1, feat).
// SBF: self-loop output is bf16 (layer1 -> h1) vs fp32 (layer2 -> out).
// Epilogue: double-buffered LDS staging + coalesced 16B stores; phases are
// separated by lgkm-only barriers so global stores stay in flight (no
// per-relation vmcnt(0) drain).
// ---------------------------------------------------------------------------
template<int H, int RT, bool ABF, bool SBF>
__global__ __launch_bounds__(512) void gemm_rel_mfma(
    const void* __restrict__ Av, const unsigned short* __restrict__ Wt,
    const float* __restrict__ bias,
    unsigned short* __restrict__ C, void* __restrict__ Cselfv,
    int N, int Rrt, int relu)
{
    constexpr int AS = 72;   // 144 B/row = 36 words = 4 mod 32 -> 2-way (free)
    constexpr int CPB = (H == 64) ? 72 : 40;   // bf16 staging stride (16B-aligned rows)
    __shared__ unsigned short As[64 * AS];
    alignas(16) __shared__ float Csf[2][64 * 36];  // dbuf staging (bf16/fp32 union)
    const int R = RT ? RT : Rrt;
    const int tid = threadIdx.x;
    const int n0 = blockIdx.x * 64;

    if constexpr (ABF) {
        // bf16 input: 64x64 = 4096 ushorts = exactly 512 short8 slots.
        const unsigned short* A = (const unsigned short*)Av;
        int n = tid >> 3, d8 = (tid & 7) * 8;
        int gn = n0 + n;
        short8 u = {};
        if (gn < N) u = *(const short8*)&A[(size_t)gn * 64 + d8];
        if (relu) {
            #pragma unroll
            for (int j = 0; j < 8; ++j) {
                unsigned short x = (unsigned short)u[j];
                u[j] = (short)((x & 0x8000) ? 0 : x);   // bf16 relu = sign test
            }
        }
        *(short8*)&As[n * AS + d8] = u;
    } else {
        const float* A = (const float*)Av;
        #pragma unroll
        for (int i = 0; i < 2; ++i) {
            int lin = tid + i * 512;
            int n = lin >> 4;
            int d4 = (lin & 15) * 4;
            int gn = n0 + n;
            float4 v = make_float4(0.f, 0.f, 0.f, 0.f);
            if (gn < N) v = *(const float4*)&A[(size_t)gn * 64 + d4];
            if (relu) {
                v.x = fmaxf(v.x, 0.f); v.y = fmaxf(v.y, 0.f);
                v.z = fmaxf(v.z, 0.f); v.w = fmaxf(v.w, 0.f);
            }
            ushort4 u;
            u.x = f2bf(v.x); u.y = f2bf(v.y); u.z = f2bf(v.z); u.w = f2bf(v.w);
            *(ushort4*)&As[n * AS + d4] = u;
        }
    }

    const int w = tid >> 6, lane = tid & 63;
    const int m = lane & 15, quad = lane >> 4;
    const int wt = w & 3;        // node sub-tile (16 nodes)
    const int half = w >> 2;     // column half (H/2 cols)

    lds_barrier();

    // Node fragment (B operand): B[k][n=lane&15] = feat[node][k].
    short8 afrag[2];
    afrag[0] = *(const short8*)&As[(wt * 16 + m) * AS + 0 * 32 + quad * 8];
    afrag[1] = *(const short8*)&As[(wt * 16 + m) * AS + 1 * 32 + quad * 8];

    constexpr int NT = H / 32;   // col-tiles per wave (64->2, 32->1)

    auto wptr = [&](int r, int nt, int kc) {
        int colbase = half * (H / 2) + nt * 16;
        return (const short8*)&Wt[((size_t)(r * H + colbase + m)) * 64 + kc * 32 + quad * 8];
    };

    short8 wf0[NT][2], wf1[NT][2];
    #pragma unroll
    for (int nt = 0; nt < NT; ++nt) { wf0[nt][0] = *wptr(0, nt, 0); wf0[nt][1] = *wptr(0, nt, 1); }
    #pragma unroll
    for (int nt = 0; nt < NT; ++nt) { wf1[nt][0] = *wptr(1, nt, 0); wf1[nt][1] = *wptr(1, nt, 1); }

    #pragma unroll
    for (int r = 0; r <= R; ++r) {
        short8 wn[NT][2];
        if (r + 2 <= R) {
            #pragma unroll
            for (int nt = 0; nt < NT; ++nt) {
                wn[nt][0] = *wptr(r + 2, nt, 0);
                wn[nt][1] = *wptr(r + 2, nt, 1);
            }
        }

        f32x4 acc[NT];
        #pragma unroll
        for (int nt = 0; nt < NT; ++nt) {
            acc[nt] = (f32x4){0.f, 0.f, 0.f, 0.f};
            acc[nt] = __builtin_amdgcn_mfma_f32_16x16x32_bf16(wf0[nt][0], afrag[0], acc[nt], 0, 0, 0);
            acc[nt] = __builtin_amdgcn_mfma_f32_16x16x32_bf16(wf0[nt][1], afrag[1], acc[nt], 0, 0, 0);
        }

        // ---- stage into Csf[r&1] ----
        // D layout (swapped): reg i -> h-col = colbase + quad*4 + i, lane&15 -> node.
        unsigned short* Cb = (unsigned short*)Csf[r & 1];
        float* Cf = Csf[r & 1];
        if (r < R) {
            #pragma unroll
            for (int nt = 0; nt < NT; ++nt) {
                int col = half * (H / 2) + nt * 16 + quad * 4;
                ushort4 u;
                u.x = f2bf(acc[nt][0]); u.y = f2bf(acc[nt][1]);
                u.z = f2bf(acc[nt][2]); u.w = f2bf(acc[nt][3]);
                *(ushort4*)&Cb[(wt * 16 + m) * CPB + col] = u;
            }
        } else if constexpr (SBF) {
            #pragma unroll
            for (int nt = 0; nt < NT; ++nt) {
                int col = half * (H / 2) + nt * 16 + quad * 4;
                const float4 bv = *(const float4*)&bias[col];
                ushort4 u;
                u.x = f2bf(acc[nt][0] + bv.x); u.y = f2bf(acc[nt][1] + bv.y);
                u.z = f2bf(acc[nt][2] + bv.z); u.w = f2bf(acc[nt][3] + bv.w);
                *(ushort4*)&Cb[(wt * 16 + m) * CPB + col] = u;
            }
        } else {
            #pragma unroll
            for (int nt = 0; nt < NT; ++nt) {
                int col = half * (H / 2) + nt * 16 + quad * 4;
                const float4 bv = *(const float4*)&bias[col];
                float4 o = make_float4(acc[nt][0] + bv.x, acc[nt][1] + bv.y,
                                       acc[nt][2] + bv.z, acc[nt][3] + bv.w);
                *(float4*)&Cf[(wt * 16 + m) * 36 + col] = o;
            }
        }

        lds_barrier();   // lgkm-only: stage(r) visible; r-1 readout reads done

        // ---- coalesced readout from Csf[r&1] ----
        if (r < R) {
            if (H == 64) {
                int rw = tid >> 3, ch = tid & 7;      // 64 rows x 8 chunks of 16B
                int gn = n0 + rw;
                if (gn < N) {
                    uint4 v = *(const uint4*)&Cb[rw * CPB + ch * 8];
                    *(uint4*)&C[((size_t)r * N + gn) * H + ch * 8] = v;
                }
            } else {
                if (tid < 256) {
                    int rw = tid >> 2, ch = tid & 3;  // 64 rows x 4 chunks of 16B
                    int gn = n0 + rw;
                    if (gn < N) {
                        uint4 v = *(const uint4*)&Cb[rw * CPB + ch * 8];
                        *(uint4*)&C[((size_t)r * N + gn) * H + ch * 8] = v;
                    }
                }
            }
        } else if constexpr (SBF) {
            unsigned short* Cs = (unsigned short*)Cselfv;
            int rw = tid >> 3, ch = tid & 7;
            int gn = n0 + rw;
            if (gn < N) {
                uint4 v = *(const uint4*)&Cb[rw * CPB + ch * 8];
                *(uint4*)&Cs[(size_t)gn * H + ch * 8] = v;
            }
        } else {
            float* outf = (float*)Cselfv;
            int rw = tid >> 3, ch = tid & 7;          // 64 rows x 8 float4
            int gn = n0 + rw;
            if (gn < N) {
                float4 v = *(const float4*)&Cf[rw * 36 + ch * 4];
                *(float4*)&outf[(size_t)gn * 32 + ch * 4] = v;
            }
        }

        #pragma unroll
        for (int nt = 0; nt < NT; ++nt) {
            wf0[nt][0] = wf1[nt][0]; wf0[nt][1] = wf1[nt][1];
            wf1[nt][0] = wn[nt][0];  wf1[nt][1] = wn[nt][1];
        }
    }
}

// ---------------------------------------------------------------------------
// Bucket partition. Bucket = 64 consecutive dst nodes.
// Record: (et*N + src) << 6 | (dst & 63).
// ---------------------------------------------------------------------------
__global__ __launch_bounds__(256) void zero_int(int* __restrict__ p, int n) {
    int i = blockIdx.x * 256 + threadIdx.x;
    if (i < n) p[i] = 0;
}

__global__ __launch_bounds__(256) void fine_hist(
    const int* __restrict__ dst, int* __restrict__ ghist, int E, int B, int CH)
{
    __shared__ int hist[MAXB];
    const int t = threadIdx.x;
    const int e0 = blockIdx.x * CH, e1 = min(E, e0 + CH);
    for (int i = t; i < B; i += 256) hist[i] = 0;
    __syncthreads();
    for (int e = e0 + t; e < e1; e += 256) atomicAdd(&hist[dst[e] >> 6], 1);
    __syncthreads();
    for (int i = t; i < B; i += 256) {
        int h = hist[i];
        if (h) atomicAdd(&ghist[i], h);
    }
}

__global__ __launch_bounds__(256) void fine_scan(
    const int* __restrict__ ghist, int* __restrict__ bstart,
    int* __restrict__ cursor, int B, int E)
{
    __shared__ int ts[256];
    const int t = threadIdx.x;
    const int PER = (B + 255) / 256;   // <= 8
    int loc[8];
    int s = 0;
    for (int j = 0; j < PER; ++j) {
        int i = t * PER + j;
        loc[j] = (i < B) ? ghist[i] : 0;
        s += loc[j];
    }
    ts[t] = s;
    __syncthreads();
    for (int off = 1; off < 256; off <<= 1) {
        int x = (t >= off) ? ts[t - off] : 0;
        __syncthreads();
        ts[t] += x;
        __syncthreads();
    }
    int run = ts[t] - s;
    for (int j = 0; j < PER; ++j) {
        int i = t * PER + j;
        if (i < B) { bstart[i] = run; cursor[i] = run; }
        run += loc[j];
    }
    if (t == 255) bstart[B] = E;
}

__global__ __launch_bounds__(256) void partition_fine(
    const int* __restrict__ src, const int* __restrict__ dst,
    const int* __restrict__ et, int* __restrict__ cursor,
    int* __restrict__ rec, int E, int N, int B, int CH)
{
    __shared__ int hist[MAXB];
    __shared__ int base[MAXB];
    __shared__ int cnt[MAXB];
    const int t = threadIdx.x;
    const int e0 = blockIdx.x * CH, e1 = min(E, e0 + CH);

    for (int i = t; i < B; i += 256) hist[i] = 0;
    __syncthreads();
    for (int e = e0 + t; e < e1; e += 256) atomicAdd(&hist[dst[e] >> 6], 1);
    __syncthreads();
    for (int i = t; i < B; i += 256) {
        int h = hist[i];
        base[i] = h ? atomicAdd(&cursor[i], h) : 0;
        cnt[i] = 0;
    }
    __syncthreads();
    for (int e = e0 + t; e < e1; e += 256) {
        int d = dst[e];
        int b = d >> 6;
        int pos = base[b] + atomicAdd(&cnt[b], 1);
        rec[pos] = ((et[e] * N + src[e]) << 6) | (d & 63);
    }
}

// ---------------------------------------------------------------------------
// Per-bucket counting sort -> per-node CSR (row_ptr + eidx).
// ---------------------------------------------------------------------------
__global__ __launch_bounds__(256) void bucket_sort(
    const int* __restrict__ bstart, const int* __restrict__ rec,
    int* __restrict__ eidx, int* __restrict__ row_ptr, int N, int E)
{
    __shared__ int hist[64];
    __shared__ int excl[64];
    __shared__ int cur[64];
    const int b = blockIdx.x;
    const int tid = threadIdx.x;
    const int p0 = bstart[b], p1 = bstart[b + 1];

    if (tid < 64) hist[tid] = 0;
    __syncthreads();
    for (int p = p0 + tid; p < p1; p += 256)
        atomicAdd(&hist[rec[p] & 63], 1);
    __syncthreads();
    if (tid == 0) {
        int run = 0;
        #pragma unroll
        for (int i = 0; i < 64; ++i) { excl[i] = run; run += hist[i]; }
    }
    __syncthreads();
    if (tid < 64) {
        cur[tid] = excl[tid];
        int n = b * 64 + tid;
        if (n < N) row_ptr[n] = p0 + excl[tid];
    }
    if (b == 0 && tid == 0) row_ptr[N] = E;
    __syncthreads();
    for (int p = p0 + tid; p < p1; p += 256) {
        int rv = rec[p];
        int pos = p0 + atomicAdd(&cur[rv & 63], 1);
        eidx[pos] = rv >> 6;   // et*N + src
    }
}

// ---------------------------------------------------------------------------
// agg64: one 64-lane wave per dst node. Lane loads a packed uint (2 bf16
// cols); the two 32-lane halves walk alternate edges (2-edge MLP + 4-deep
// unroll = 8 in flight). Combine via shfl; h1 is bf16 (packed uint I/O).
// ---------------------------------------------------------------------------
__global__ __launch_bounds__(256) void agg_csr64(
    const unsigned int* __restrict__ hw32, const int* __restrict__ row_ptr,
    const int* __restrict__ eidx, unsigned int* __restrict__ out32, int N)
{
    const int d = blockIdx.x * 4 + (threadIdx.x >> 6);
    const int lane = threadIdx.x & 63;
    if (d >= N) return;
    const int he = lane >> 5;     // which edge of each pair
    const int c = lane & 31;      // uint col (2 bf16 cols)
    const int p0 = row_ptr[d], p1 = row_ptr[d + 1];
    float s0 = 0.f, s1 = 0.f, t0 = 0.f, t1 = 0.f;
    int p = p0 + he;
    for (; p + 6 < p1; p += 8) {
        unsigned int v0 = hw32[(size_t)eidx[p]     * 32 + c];
        unsigned int v1 = hw32[(size_t)eidx[p + 2] * 32 + c];
        unsigned int v2 = hw32[(size_t)eidx[p + 4] * 32 + c];
        unsigned int v3 = hw32[(size_t)eidx[p + 6] * 32 + c];
        s0 += bf2f((unsigned short)(v0 & 0xffff)); s1 += bf2f((unsigned short)(v0 >> 16));
        t0 += bf2f((unsigned short)(v1 & 0xffff)); t1 += bf2f((unsigned short)(v1 >> 16));
        s0 += bf2f((unsigned short)(v2 & 0xffff)); s1 += bf2f((unsigned short)(v2 >> 16));
        t0 += bf2f((unsigned short)(v3 & 0xffff)); t1 += bf2f((unsigned short)(v3 >> 16));
    }
    for (; p < p1; p += 2) {
        unsigned int v = hw32[(size_t)eidx[p] * 32 + c];
        s0 += bf2f((unsigned short)(v & 0xffff)); s1 += bf2f((unsigned short)(v >> 16));
    }
    s0 += t0; s1 += t1;
    float u0 = __shfl(s0, c + 32, 64);   // partner in upper half
    float u1 = __shfl(s1, c + 32, 64);
    if (he == 0) {
        unsigned int cur = out32[(size_t)d * 32 + c];
        float o0 = s0 + u0 + bf2f((unsigned short)(cur & 0xffff));
        float o1 = s1 + u1 + bf2f((unsigned short)(cur >> 16));
        out32[(size_t)d * 32 + c] = (unsigned int)f2bf(o0) | ((unsigned int)f2bf(o1) << 16);
    }
}

// ---------------------------------------------------------------------------
// agg32: 32 lanes per dst node (8 nodes/block); 16-lane halves walk alternate
// edges with packed-uint loads; combine via shfl; out is fp32 (d_out).
// ---------------------------------------------------------------------------
__global__ __launch_bounds__(256) void agg_csr32(
    const unsigned int* __restrict__ hw32, const int* __restrict__ row_ptr,
    const int* __restrict__ eidx, float* __restrict__ out, int N)
{
    const int d = blockIdx.x * 8 + (threadIdx.x >> 5);
    const int l = threadIdx.x & 31;
    if (d >= N) return;
    const int he = l >> 4;
    const int c = l & 15;         // uint col (2 bf16 cols of 32)
    const int p0 = row_ptr[d], p1 = row_ptr[d + 1];
    float s0 = 0.f, s1 = 0.f, t0 = 0.f, t1 = 0.f;
    int p = p0 + he;
    for (; p + 6 < p1; p += 8) {
        unsigned int v0 = hw32[(size_t)eidx[p]     * 16 + c];
        unsigned int v1 = hw32[(size_t)eidx[p + 2] * 16 + c];
        unsigned int v2 = hw32[(size_t)eidx[p + 4] * 16 + c];
        unsigned int v3 = hw32[(size_t)eidx[p + 6] * 16 + c];
        s0 += bf2f((unsigned short)(v0 & 0xffff)); s1 += bf2f((unsigned short)(v0 >> 16));
        t0 += bf2f((unsigned short)(v1 & 0xffff)); t1 += bf2f((unsigned short)(v1 >> 16));
        s0 += bf2f((unsigned short)(v2 & 0xffff)); s1 += bf2f((unsigned short)(v2 >> 16));
        t0 += bf2f((unsigned short)(v3 & 0xffff)); t1 += bf2f((unsigned short)(v3 >> 16));
    }
    for (; p < p1; p += 2) {
        unsigned int v = hw32[(size_t)eidx[p] * 16 + c];
        s0 += bf2f((unsigned short)(v & 0xffff)); s1 += bf2f((unsigned short)(v >> 16));
    }
    s0 += t0; s1 += t1;
    float u0 = __shfl(s0, (threadIdx.x & 63) ^ 16, 64);
    float u1 = __shfl(s1, (threadIdx.x & 63) ^ 16, 64);
    if (he == 0) {
        float2 cur = *(const float2*)&out[(size_t)d * 32 + c * 2];
        float2 o = make_float2(cur.x + s0 + u0, cur.y + s1 + u1);
        *(float2*)&out[(size_t)d * 32 + c * 2] = o;
    }
}

extern "C" void kernel_launch(void* const* d_in, const int* in_sizes, int n_in,
                              void* d_out, int out_size, void* d_ws, size_t ws_size,
                              hipStream_t stream)
{
    const float* feat = (const float*)d_in[0];
    const int*   src  = (const int*)d_in[1];
    const int*   dst  = (const int*)d_in[2];
    const int*   et   = (const int*)d_in[3];
    const float* W1   = (const float*)d_in[4];
    const float* Ws1  = (const float*)d_in[5];
    const float* b1   = (const float*)d_in[6];
    const float* W2   = (const float*)d_in[7];
    const float* Ws2  = (const float*)d_in[8];
    const float* b2   = (const float*)d_in[9];
    float* out = (float*)d_out;

    const int N = in_sizes[0] / 64;           // 100000
    const int E = in_sizes[1];                // 1600000
    const int R = in_sizes[4] / (64 * 64);    // 8
    const int B = (N + 63) / 64;              // 1563 fine buckets

    // Workspace layout
    unsigned short* hW  = (unsigned short*)d_ws;           // [R][N][64] bf16 (reused [R][N][32])
    unsigned short* h1  = hW + (size_t)R * N * 64;         // [N][64] bf16
    unsigned short* Wt1 = h1 + (size_t)N * 64;             // [(R+1)*64*64]
    unsigned short* Wt2 = Wt1 + (size_t)(R + 1) * 64 * 64; // [(R+1)*32*64]
    int*   ghist   = (int*)(Wt2 + (size_t)(R + 1) * 32 * 64);  // [B]
    int*   bstart  = ghist + B;                            // [B+1]
    int*   cursor  = bstart + (B + 1);                     // [B]
    int*   row_ptr = cursor + B;                           // [N+1]
    int*   rec     = row_ptr + (N + 1);                    // [E]
    int*   eidx    = rec + E;                              // [E]

    const dim3 blk(256);
    const int nblk64 = (N + 63) / 64;
    const int P  = 512;                       // partition blocks
    const int CH = (E + P - 1) / P;           // 3125 edges per block

    // ---- Weight pre-transpose (bf16, [r][h][d]) ----
    transpose_w<64><<<((R + 1) * 64 * 64 + 255) / 256, blk, 0, stream>>>(W1, Ws1, Wt1, R);
    transpose_w<32><<<((R + 1) * 32 * 64 + 255) / 256, blk, 0, stream>>>(W2, Ws2, Wt2, R);

    // ---- Build per-node CSR via bucket partition + per-bucket sort ----
    zero_int<<<(B + 255) / 256, blk, 0, stream>>>(ghist, B);
    fine_hist<<<P, blk, 0, stream>>>(dst, ghist, E, B, CH);
    fine_scan<<<1, blk, 0, stream>>>(ghist, bstart, cursor, B, E);
    partition_fine<<<P, blk, 0, stream>>>(src, dst, et, cursor, rec, E, N, B, CH);
    bucket_sort<<<B, blk, 0, stream>>>(bstart, rec, eidx, row_ptr, N, E);

    // ---- Layer 1 ---- (hW1 bf16 + self-loop bf16 into h1, fused)
    if (R == 8)
        gemm_rel_mfma<64, 8, false, true><<<nblk64, 512, 0, stream>>>(feat, Wt1, b1, hW, h1, N, R, 0);
    else
        gemm_rel_mfma<64, 0, false, true><<<nblk64, 512, 0, stream>>>(feat, Wt1, b1, hW, h1, N, R, 0);
    agg_csr64<<<dim3((N + 3) / 4), blk, 0, stream>>>((const unsigned int*)hW, row_ptr, eidx,
                                                     (unsigned int*)h1, N);

    // ---- Layer 2 ---- (bf16 A staging with bit-mask ReLU; self fp32 -> out)
    if (R == 8)
        gemm_rel_mfma<32, 8, true, false><<<nblk64, 512, 0, stream>>>(h1, Wt2, b2, hW, out, N, R, 1);
    else
        gemm_rel_mfma<32, 0, true, false><<<nblk64, 512, 0, stream>>>(h1, Wt2, b2, hW, out, N, R, 1);
    agg_csr32<<<dim3((N + 7) / 8), blk, 0, stream>>>((const unsigned int*)hW, row_ptr, eidx, out, N);
}